// Round 1
// baseline (1341.736 us; speedup 1.0000x reference)
//
#include <hip/hip_runtime.h>
#include <math.h>

typedef _Float16 f16;
typedef __attribute__((ext_vector_type(8))) _Float16 half8;
typedef __attribute__((ext_vector_type(4))) float floatx4;

#define NB 8192

// ======================= weight conversion =======================
// dst[u][n][k] = src[u*K*N + k*N + n] * scale   (transpose to k-contiguous)
struct ConvJob { const float* src; f16* dst; int K; int N; int ucount; float scale; };
struct ConvJobs { ConvJob j[28]; };

__global__ void convert_w(ConvJobs JJ) {
    ConvJob jb = JJ.j[blockIdx.z];
    int u = blockIdx.x;
    if (u >= jb.ucount) return;
    __shared__ f16 tile[128 * 136];
    const int K = jb.K, N = jb.N;
    const int npad = N + 8;
    const int nsh = (N == 128) ? 7 : 6;
    const int ksh = (K == 128) ? 7 : 6;
    const float* src = jb.src + (size_t)u * K * N;
    for (int idx = threadIdx.x; idx < K * N; idx += 256) {
        int k = idx >> nsh, n = idx & (N - 1);
        tile[k * npad + n] = (f16)(src[idx] * jb.scale);
    }
    __syncthreads();
    f16* dst = jb.dst + (size_t)u * N * K;
    for (int idx = threadIdx.x; idx < N * K; idx += 256) {
        int n = idx >> ksh, k = idx & (K - 1);
        dst[idx] = tile[k * npad + n];
    }
}

// ======================= x -> planar f16 =======================
__global__ void x_to_planes(const float* __restrict__ x, f16* s_p, f16* v0, f16* v1, f16* v2) {
    int t = blockIdx.x * 256 + threadIdx.x;
    if (t >= NB * 64) return;
    int b = t >> 6, u = t & 63;
    const float* xr = x + (size_t)b * 256;
    s_p[t] = (f16)xr[u];
    v0[t] = (f16)xr[64 + 3 * u + 0];
    v1[t] = (f16)xr[64 + 3 * u + 1];
    v2[t] = (f16)xr[64 + 3 * u + 2];
}

// ======================= tensor-product unit =======================
// out[b,w] = sum_u p[b,u] * sum_v q[b,v] * Wt[u][w][v]
struct TpJob { const f16* p; const f16* q; const f16* w; float* out; int pstride; int qstride; };
struct TpJobs { TpJob j[10]; };

template <int M>
__launch_bounds__(256, 2)
__global__ void tp_unit(TpJobs JJ) {
    TpJob jb = JJ.j[blockIdx.z];
    constexpr int KC = M / 32;            // 32-wide k chunks per u-step
    constexpr int NP = M + 8;             // padded LDS row (halfs), keeps 16B align
    constexpr int PR = M / 8;             // int4 pieces per row
    constexpr int PPT = 128 * M / 8 / 256;// int4 pieces per thread per slab
    __shared__ f16 p_lds[128 * NP];
    __shared__ f16 w_lds[128 * NP];
    const int tid = threadIdx.x;
    const int lane = tid & 63;
    const int wave = tid >> 6;
    const int wm = wave & 1, wn = wave >> 1;
    const int l15 = lane & 15, quad = lane >> 4;
    const int rowBase = blockIdx.x * 128;

    // stage p plane -> LDS (padded rows)
    #pragma unroll
    for (int t = 0; t < PPT; t++) {
        int idx = t * 256 + tid;
        int r = idx / PR, pc = idx % PR;
        *(int4*)&p_lds[r * NP + pc * 8] =
            *(const int4*)(jb.p + (size_t)(rowBase + r) * jb.pstride + pc * 8);
    }
    // Q fragments live in registers for the whole kernel (A-operand)
    half8 qf[4][KC];
    for (int t = 0; t < 4; t++) {
        int row = rowBase + wm * 64 + t * 16 + l15;
        const f16* qr = jb.q + (size_t)row * jb.qstride;
        #pragma unroll
        for (int c = 0; c < KC; c++) qf[t][c] = *(const half8*)(qr + c * 32 + quad * 8);
    }
    floatx4 acc[4][4];
    #pragma unroll
    for (int a = 0; a < 4; a++)
        #pragma unroll
        for (int b = 0; b < 4; b++) acc[a][b] = (floatx4){0.f, 0.f, 0.f, 0.f};

    // prefetch W(u=0) into registers
    int4 wbuf[PPT];
    #pragma unroll
    for (int t = 0; t < PPT; t++)
        wbuf[t] = *(const int4*)(jb.w + (size_t)(t * 256 + tid) * 8);

    for (int u = 0; u < M; u++) {
        __syncthreads();   // previous iter's reads done (also covers p_lds at u=0)
        #pragma unroll
        for (int t = 0; t < PPT; t++) {
            int idx = t * 256 + tid;
            int r = idx / PR, pc = idx % PR;
            *(int4*)&w_lds[r * NP + pc * 8] = wbuf[t];
        }
        if (u + 1 < M) {
            const f16* wu = jb.w + (size_t)(u + 1) * (128 * M);
            #pragma unroll
            for (int t = 0; t < PPT; t++)
                wbuf[t] = *(const int4*)(wu + (size_t)(t * 256 + tid) * 8);
        }
        __syncthreads();

        // p scalars: one per m-tile (all frag elems of a lane share one row)
        half8 p8[4];
        #pragma unroll
        for (int t = 0; t < 4; t++) {
            f16 pv = p_lds[(wm * 64 + t * 16 + l15) * NP + u];
            p8[t] = (half8){pv, pv, pv, pv, pv, pv, pv, pv};
        }
        #pragma unroll
        for (int c = 0; c < KC; c++) {
            half8 af[4];
            #pragma unroll
            for (int t = 0; t < 4; t++) af[t] = qf[t][c] * p8[t];   // v_pk_mul_f16
            #pragma unroll
            for (int nt = 0; nt < 4; nt++) {
                half8 bf = *(const half8*)&w_lds[(wn * 64 + nt * 16 + l15) * NP + c * 32 + quad * 8];
                #pragma unroll
                for (int t = 0; t < 4; t++)
                    acc[t][nt] = __builtin_amdgcn_mfma_f32_16x16x32_f16(af[t], bf, acc[t][nt], 0, 0, 0);
            }
        }
    }
    // epilogue (verified C/D mapping: col=lane&15, row=quad*4+reg)
    #pragma unroll
    for (int t = 0; t < 4; t++)
        #pragma unroll
        for (int nt = 0; nt < 4; nt++) {
            int col = wn * 64 + nt * 16 + l15;
            float* orow = jb.out + (size_t)(rowBase + wm * 64 + t * 16 + quad * 4) * 128 + col;
            #pragma unroll
            for (int r = 0; r < 4; r++) orow[(size_t)r * 128] = acc[t][nt][r];
        }
}

// ======================= generic small GEMM =======================
// out[b, n] = sum_k A[b,k] * W[n*K + k], with epilogue modes
struct SmallJob { const f16* A; const f16* W; char* out; int astride; int ostride;
                  int ocol; int cstride; int mode; int Njob; int ny; };
struct SmallJobs { SmallJob j[4]; };

template <int K>
__launch_bounds__(256, 2)
__global__ void small_gemm(SmallJobs JJ) {
    SmallJob jb = JJ.j[blockIdx.z];
    if ((int)blockIdx.y >= jb.ny) return;
    constexpr int KC = K / 32;
    constexpr int NP = K + 8;
    constexpr int PR = K / 8;
    constexpr int PPT = 128 * K / 8 / 256;
    __shared__ f16 w_lds[128 * NP];
    const int tid = threadIdx.x, lane = tid & 63, wave = tid >> 6;
    const int wm = wave & 1, wn = wave >> 1;
    const int l15 = lane & 15, quad = lane >> 4;
    const int rowBase = blockIdx.x * 128;
    const int nBase = blockIdx.y * 128;

    #pragma unroll
    for (int t = 0; t < PPT; t++) {
        int idx = t * 256 + tid;
        int r = idx / PR, pc = idx % PR;
        int4 v = {0, 0, 0, 0};
        if (nBase + r < jb.Njob)
            v = *(const int4*)(jb.W + (size_t)(nBase + r) * K + pc * 8);
        *(int4*)&w_lds[r * NP + pc * 8] = v;
    }
    half8 qf[4][KC];
    for (int t = 0; t < 4; t++) {
        int row = rowBase + wm * 64 + t * 16 + l15;
        const f16* ar = jb.A + (size_t)row * jb.astride;
        #pragma unroll
        for (int c = 0; c < KC; c++) qf[t][c] = *(const half8*)(ar + c * 32 + quad * 8);
    }
    floatx4 acc[4][4];
    #pragma unroll
    for (int a = 0; a < 4; a++)
        #pragma unroll
        for (int b = 0; b < 4; b++) acc[a][b] = (floatx4){0.f, 0.f, 0.f, 0.f};
    __syncthreads();
    #pragma unroll
    for (int c = 0; c < KC; c++)
        #pragma unroll
        for (int nt = 0; nt < 4; nt++) {
            half8 bf = *(const half8*)&w_lds[(wn * 64 + nt * 16 + l15) * NP + c * 32 + quad * 8];
            #pragma unroll
            for (int t = 0; t < 4; t++)
                acc[t][nt] = __builtin_amdgcn_mfma_f32_16x16x32_f16(qf[t][c], bf, acc[t][nt], 0, 0, 0);
        }
    const float GAIN = 1.5927116870880127f;
    #pragma unroll
    for (int t = 0; t < 4; t++)
        #pragma unroll
        for (int nt = 0; nt < 4; nt++) {
            int col = nBase + wn * 64 + nt * 16 + l15;
            if (col >= jb.Njob) continue;
            int rowB = rowBase + wm * 64 + t * 16 + quad * 4;
            #pragma unroll
            for (int r = 0; r < 4; r++) {
                float v = acc[t][nt][r];
                size_t ro = (size_t)(rowB + r) * jb.ostride;
                if (jb.mode == 0)      ((f16*)jb.out)[ro + jb.ocol + col] = (f16)v;
                else if (jb.mode == 1) ((f16*)jb.out)[ro + jb.ocol + col] = (f16)(GAIN * tanhf(v));
                else                   ((float*)jb.out)[ro + jb.ocol + (size_t)col * jb.cstride] = v;
            }
        }
}

// ======================= elementwise =======================
__global__ void tp_reduce(const float* __restrict__ P, f16* s_tp, f16* v0, f16* v1, f16* v2) {
    int t = blockIdx.x * 256 + threadIdx.x;
    if (t >= NB * 128) return;
    const size_t S = (size_t)NB * 128;
    s_tp[t] = (f16)(P[t] + P[S + t] + P[2 * S + t] + P[3 * S + t]);
    v0[t] = (f16)(P[4 * S + t] + P[7 * S + t]);
    v1[t] = (f16)(P[5 * S + t] + P[8 * S + t]);
    v2[t] = (f16)(P[6 * S + t] + P[9 * S + t]);
}

__global__ void vgate(const f16* __restrict__ sg_gg,
                      const f16* vl0, const f16* vl1, const f16* vl2,
                      f16* vg0, f16* vg1, f16* vg2) {
    int t = blockIdx.x * 256 + threadIdx.x;
    if (t >= NB * 128) return;
    int b = t >> 7, c = t & 127;
    float g = (float)sg_gg[(size_t)b * 256 + 128 + c];
    vg0[t] = (f16)(g * (float)vl0[t]);
    vg1[t] = (f16)(g * (float)vl1[t]);
    vg2[t] = (f16)(g * (float)vl2[t]);
}

// ======================= host launcher =======================
extern "C" void kernel_launch(void* const* d_in, const int* in_sizes, int n_in,
                              void* d_out, int out_size, void* d_ws, size_t ws_size,
                              hipStream_t stream) {
    const float* x = (const float*)d_in[0];
    const float* W_IN[28];
    for (int i = 0; i < 28; i++) W_IN[i] = (const float*)d_in[1 + i];
    // order: 0 b1_l1_w0, 1 b1_l1_w1, 2 b1_l2_w0, 3 b1_l2_w1, 4 ss, 5 vv, 6 sv, 7 vs,
    //        8 g_ws, 9 g_wg, 10 g_wv, 11 o_w0, 12 o_w1, 13..25 same for b2, 26 f_w0, 27 f_w1

    char* base = (char*)d_ws;
    size_t off = 0;
    auto alloc = [&](size_t bytes) -> char* {
        char* p = base + off;
        off += (bytes + 255) & ~(size_t)255;
        return p;
    };
    const size_t S128 = (size_t)NB * 128;

    // ---- converted weights (f16) ----
    f16* Wl12_b1_s = (f16*)alloc(8192 * 2);
    f16* Wl12_b1_v = (f16*)alloc(8192 * 2);
    f16* Wl12_b2_s = (f16*)alloc(32768 * 2);
    f16* Wl12_b2_v = (f16*)alloc(32768 * 2);
    f16* Wtp_b1[4]; for (int i = 0; i < 4; i++) Wtp_b1[i] = (f16*)alloc((size_t)64 * 128 * 64 * 2);
    f16* Wtp_b2[4]; for (int i = 0; i < 4; i++) Wtp_b2[i] = (f16*)alloc((size_t)128 * 128 * 128 * 2);
    f16* Wg_b1_sg = (f16*)alloc(32768 * 2);
    f16* Wg_b1_v  = (f16*)alloc(16384 * 2);
    f16* Wg_b2_sg = (f16*)alloc(32768 * 2);
    f16* Wg_b2_v  = (f16*)alloc(16384 * 2);
    f16* Wo_b1_s = (f16*)alloc(16384 * 2);
    f16* Wo_b1_v = (f16*)alloc(16384 * 2);
    f16* Wo_b2_s = (f16*)alloc(16384 * 2);
    f16* Wo_b2_v = (f16*)alloc(16384 * 2);
    f16* Wf_s = (f16*)alloc(8192 * 2);
    f16* Wf_v = (f16*)alloc(8192 * 2);
    // ---- activations ----
    f16* s_p = (f16*)alloc((size_t)NB * 64 * 2);
    f16* v_p[3]; for (int i = 0; i < 3; i++) v_p[i] = (f16*)alloc((size_t)NB * 64 * 2);
    f16* Breg = (f16*)alloc((size_t)4 * NB * 256 * 2);        // l1l2 outputs (reused b1/b2)
    float* Part = (float*)alloc((size_t)10 * S128 * 4);       // tp partials (reused)
    f16* Dreg = (f16*)alloc((size_t)4 * S128 * 2);            // s_tp + v_tp[3] (reused)
    f16* Ereg = (f16*)alloc((size_t)8 * S128 * 2);            // sg_gg(2) + vl(3) + vg(3) (reused)
    f16* Freg = (f16*)alloc((size_t)4 * S128 * 2);            // o-lin outputs (reused)
    (void)ws_size; (void)in_sizes; (void)n_in; (void)out_size;

    const float c_l1 = 0.125f;                       // 1/sqrt(64)
    const float c128 = 0.088388347648318447f;        // 1/sqrt(128)
    const float c1 = 1.0f / (64.0f * 1.4142135623730951f);
    const float c2 = 1.0f / (128.0f * 1.4142135623730951f);
    const float i3 = 0.57735026918962584f;           // 1/sqrt(3)

    // ---- 1. weight conversion ----
    ConvJobs CJ;
    int jn = 0;
    auto CV = [&](const float* s, f16* d, int K, int N, int uc, float sc) {
        CJ.j[jn++] = ConvJob{s, d, K, N, uc, sc};
    };
    CV(W_IN[0], Wl12_b1_s, 64, 64, 1, c_l1);  CV(W_IN[2], Wl12_b1_s + 4096, 64, 64, 1, c_l1);
    CV(W_IN[1], Wl12_b1_v, 64, 64, 1, c_l1);  CV(W_IN[3], Wl12_b1_v + 4096, 64, 64, 1, c_l1);
    CV(W_IN[13], Wl12_b2_s, 128, 128, 1, c128); CV(W_IN[15], Wl12_b2_s + 16384, 128, 128, 1, c128);
    CV(W_IN[14], Wl12_b2_v, 128, 128, 1, c128); CV(W_IN[16], Wl12_b2_v + 16384, 128, 128, 1, c128);
    CV(W_IN[4], Wtp_b1[0], 64, 128, 64, c1);  CV(W_IN[5], Wtp_b1[1], 64, 128, 64, c1 * i3);
    CV(W_IN[6], Wtp_b1[2], 64, 128, 64, c1);  CV(W_IN[7], Wtp_b1[3], 64, 128, 64, c1);
    CV(W_IN[17], Wtp_b2[0], 128, 128, 128, c2); CV(W_IN[18], Wtp_b2[1], 128, 128, 128, c2 * i3);
    CV(W_IN[19], Wtp_b2[2], 128, 128, 128, c2); CV(W_IN[20], Wtp_b2[3], 128, 128, 128, c2);
    CV(W_IN[8], Wg_b1_sg, 128, 128, 1, c128);  CV(W_IN[9], Wg_b1_sg + 16384, 128, 128, 1, c128);
    CV(W_IN[10], Wg_b1_v, 128, 128, 1, c128);
    CV(W_IN[21], Wg_b2_sg, 128, 128, 1, c128); CV(W_IN[22], Wg_b2_sg + 16384, 128, 128, 1, c128);
    CV(W_IN[23], Wg_b2_v, 128, 128, 1, c128);
    CV(W_IN[11], Wo_b1_s, 128, 128, 1, c128);  CV(W_IN[12], Wo_b1_v, 128, 128, 1, c128);
    CV(W_IN[24], Wo_b2_s, 128, 128, 1, c128);  CV(W_IN[25], Wo_b2_v, 128, 128, 1, c128);
    CV(W_IN[26], Wf_s, 128, 64, 1, c128);      CV(W_IN[27], Wf_v, 128, 64, 1, c128);
    convert_w<<<dim3(128, 1, 28), 256, 0, stream>>>(CJ);

    // ---- 2. x -> planes ----
    x_to_planes<<<NB * 64 / 256, 256, 0, stream>>>(x, s_p, v_p[0], v_p[1], v_p[2]);

    auto SJ = [](const f16* A, const f16* W, void* out, int as, int os, int oc, int cs,
                 int mode, int Nj, int ny) {
        return SmallJob{A, W, (char*)out, as, os, oc, cs, mode, Nj, ny};
    };

    // b1 plane pointers
    f16* s12 = Breg;                                  // [B][128]: s1|s2
    f16* v12[3]; for (int i = 0; i < 3; i++) v12[i] = Breg + (size_t)(1 + i) * NB * 128;
    f16* s_tp = Dreg; f16* v_tp[3]; for (int i = 0; i < 3; i++) v_tp[i] = Dreg + (1 + i) * S128;
    f16* sg_gg = Ereg;                                // [B][256]
    f16* vl[3]; for (int i = 0; i < 3; i++) vl[i] = Ereg + 2 * S128 + i * S128;
    f16* vg[3]; for (int i = 0; i < 3; i++) vg[i] = Ereg + 5 * S128 + i * S128;
    f16* s_o = Freg; f16* v_o[3]; for (int i = 0; i < 3; i++) v_o[i] = Freg + (1 + i) * S128;

    // ---- 3. b1 l1+l2 ----
    {
        SmallJobs J;
        J.j[0] = SJ(s_p, Wl12_b1_s, s12, 64, 128, 0, 1, 0, 128, 1);
        for (int i = 0; i < 3; i++) J.j[1 + i] = SJ(v_p[i], Wl12_b1_v, v12[i], 64, 128, 0, 1, 0, 128, 1);
        small_gemm<64><<<dim3(64, 1, 4), 256, 0, stream>>>(J);
    }
    // ---- 4. b1 tensor product (10 rank-1 units) ----
    {
        TpJobs J;
        J.j[0] = TpJob{s12, s12 + 64, Wtp_b1[0], Part + 0 * S128, 128, 128};
        for (int i = 0; i < 3; i++) J.j[1 + i] = TpJob{v12[i], v12[i] + 64, Wtp_b1[1], Part + (1 + i) * S128, 128, 128};
        for (int i = 0; i < 3; i++) J.j[4 + i] = TpJob{s12, v12[i] + 64, Wtp_b1[2], Part + (4 + i) * S128, 128, 128};
        for (int i = 0; i < 3; i++) J.j[7 + i] = TpJob{v12[i], s12 + 64, Wtp_b1[3], Part + (7 + i) * S128, 128, 128};
        tp_unit<64><<<dim3(64, 1, 10), 256, 0, stream>>>(J);
    }
    // ---- 5. reduce ----
    tp_reduce<<<NB * 128 / 256, 256, 0, stream>>>(Part, s_tp, v_tp[0], v_tp[1], v_tp[2]);
    // ---- 6. b1 gate GEMMs ----
    {
        SmallJobs J;
        J.j[0] = SJ(s_tp, Wg_b1_sg, sg_gg, 128, 256, 0, 1, 1, 256, 2);
        for (int i = 0; i < 3; i++) J.j[1 + i] = SJ(v_tp[i], Wg_b1_v, vl[i], 128, 128, 0, 1, 0, 128, 1);
        small_gemm<128><<<dim3(64, 2, 4), 256, 0, stream>>>(J);
    }
    // ---- 7. v gating ----
    vgate<<<NB * 128 / 256, 256, 0, stream>>>(sg_gg, vl[0], vl[1], vl[2], vg[0], vg[1], vg[2]);
    // ---- 8. b1 o-lin ----
    {
        SmallJobs J;
        J.j[0] = SJ(sg_gg, Wo_b1_s, s_o, 256, 128, 0, 1, 0, 128, 1);
        for (int i = 0; i < 3; i++) J.j[1 + i] = SJ(vg[i], Wo_b1_v, v_o[i], 128, 128, 0, 1, 0, 128, 1);
        small_gemm<128><<<dim3(64, 1, 4), 256, 0, stream>>>(J);
    }
    // b2 plane pointers (reuse regions)
    f16* s12b = Breg;                                 // [B][256]: s1|s2
    f16* v12b[3]; for (int i = 0; i < 3; i++) v12b[i] = Breg + (size_t)(1 + i) * NB * 256;
    // ---- 9. b2 l1+l2 ----
    {
        SmallJobs J;
        J.j[0] = SJ(s_o, Wl12_b2_s, s12b, 128, 256, 0, 1, 0, 256, 2);
        for (int i = 0; i < 3; i++) J.j[1 + i] = SJ(v_o[i], Wl12_b2_v, v12b[i], 128, 256, 0, 1, 0, 256, 2);
        small_gemm<128><<<dim3(64, 2, 4), 256, 0, stream>>>(J);
    }
    // ---- 10. b2 tensor product ----
    {
        TpJobs J;
        J.j[0] = TpJob{s12b, s12b + 128, Wtp_b2[0], Part + 0 * S128, 256, 256};
        for (int i = 0; i < 3; i++) J.j[1 + i] = TpJob{v12b[i], v12b[i] + 128, Wtp_b2[1], Part + (1 + i) * S128, 256, 256};
        for (int i = 0; i < 3; i++) J.j[4 + i] = TpJob{s12b, v12b[i] + 128, Wtp_b2[2], Part + (4 + i) * S128, 256, 256};
        for (int i = 0; i < 3; i++) J.j[7 + i] = TpJob{v12b[i], s12b + 128, Wtp_b2[3], Part + (7 + i) * S128, 256, 256};
        tp_unit<128><<<dim3(64, 1, 10), 256, 0, stream>>>(J);
    }
    // ---- 11. reduce ----
    tp_reduce<<<NB * 128 / 256, 256, 0, stream>>>(Part, s_tp, v_tp[0], v_tp[1], v_tp[2]);
    // ---- 12. b2 gate ----
    {
        SmallJobs J;
        J.j[0] = SJ(s_tp, Wg_b2_sg, sg_gg, 128, 256, 0, 1, 1, 256, 2);
        for (int i = 0; i < 3; i++) J.j[1 + i] = SJ(v_tp[i], Wg_b2_v, vl[i], 128, 128, 0, 1, 0, 128, 1);
        small_gemm<128><<<dim3(64, 2, 4), 256, 0, stream>>>(J);
    }
    // ---- 13. v gating ----
    vgate<<<NB * 128 / 256, 256, 0, stream>>>(sg_gg, vl[0], vl[1], vl[2], vg[0], vg[1], vg[2]);
    // ---- 14. b2 o-lin ----
    {
        SmallJobs J;
        J.j[0] = SJ(sg_gg, Wo_b2_s, s_o, 256, 128, 0, 1, 0, 128, 1);
        for (int i = 0; i < 3; i++) J.j[1 + i] = SJ(vg[i], Wo_b2_v, v_o[i], 128, 128, 0, 1, 0, 128, 1);
        small_gemm<128><<<dim3(64, 1, 4), 256, 0, stream>>>(J);
    }
    // ---- 15. final lin -> d_out (fp32, interleaved v) ----
    {
        SmallJobs J;
        J.j[0] = SJ(s_o, Wf_s, d_out, 128, 256, 0, 1, 2, 64, 1);
        for (int i = 0; i < 3; i++) J.j[1 + i] = SJ(v_o[i], Wf_v, d_out, 128, 256, 64 + i, 3, 2, 64, 1);
        small_gemm<128><<<dim3(64, 1, 4), 256, 0, stream>>>(J);
    }
}